// Round 7
// baseline (714.979 us; speedup 1.0000x reference)
//
#include <hip/hip_runtime.h>

#define N_NODES 50000
#define N_EDGES 400000
#define CSR_E (2 * N_EDGES + N_NODES) /* 850000 */
#define NCH 10       /* source chunks */
#define CHW 5000     /* chunk width in nodes: 5000*256B = 1.28MB window */
#define NE2 (N_NODES * NCH)

typedef unsigned short ushort_t;
typedef unsigned int uint_t;
typedef __attribute__((ext_vector_type(8))) short bf16x8;
typedef __attribute__((ext_vector_type(4))) float f32x4;

__device__ __forceinline__ float bf2f(ushort_t u) {
    return __uint_as_float(((uint_t)u) << 16);
}
__device__ __forceinline__ ushort_t f2bf(float f) {
    uint_t b = __float_as_uint(f);
    b += 0x7FFFu + ((b >> 16) & 1u); // RNE
    return (ushort_t)(b >> 16);
}

// ---------------- static device scratch (module BSS; d_ws untouched) ----------------
// NOTE: only reference these from device code (host sees shadow addresses - r4 fault).

__device__ int g_est;  // edge-index word stride: 1 = int32, 2 = int64
__device__ int g_is16; // 1 = float tensors bf16-packed, 0 = fp32
__device__ float g_dis_s[N_NODES];
__device__ float g_dis_r[N_NODES];
__device__ int g_cnt2[NE2];       // counts per (dst, src-chunk)
__device__ int g_offs2[NE2 + 1];  // exclusive scan + sentinel
__device__ int g_cursor2[NE2];
__device__ int g_bsum[512];
__device__ int g_bbase[512];
__device__ __align__(16) float4 g_csr[CSR_E]; // (src, out_w, in_w, unused)
__device__ __align__(16) ushort_t g_agg[(size_t)N_NODES * 256]; // bf16 [N][s128|d128]
__device__ __align__(16) ushort_t g_h1[(size_t)N_NODES * 128];  // bf16
__device__ __align__(16) ushort_t g_h2[(size_t)N_NODES * 128];  // bf16
__device__ __align__(16) ushort_t g_xcvt[(size_t)N_NODES * 128]; // bf16 (fp32-input fallback)
__device__ __align__(16) ushort_t g_bp1[8 * 128 * 32]; // B packed [kb][n][kk] bf16
__device__ __align__(16) ushort_t g_bp2[8 * 128 * 32];
__device__ __align__(16) ushort_t g_bp3[4 * 64 * 32];
__device__ float g_bc1[128];
__device__ float g_bc2[128];
__device__ float g_bro[64];

// ---------------- dtype / index-width detection ----------------

__global__ void detect_kernel(const uint_t* __restrict__ xw, const int* __restrict__ eidx) {
    if (threadIdx.x == 0 && blockIdx.x == 0) {
        int cnt = 0;
        for (int i = 0; i < 64; i++) {
            uint_t w = xw[i];
            int elo = (w >> 7) & 0xFF;
            if (elo >= 100 && elo <= 150) cnt++;
        }
        g_is16 = (cnt >= 48) ? 1 : 0;
        int any = 0;
        for (int i = 1; i < 128; i += 2) any |= eidx[i];
        g_est = any ? 1 : 2;
    }
}

// fp32-input fallback: convert x to bf16 once (no-op when already bf16)
__global__ __launch_bounds__(256) void conv_x(const float* __restrict__ x32) {
    if (g_is16) return;
    int i = blockIdx.x * 256 + threadIdx.x;
    if (i < N_NODES * 128) g_xcvt[i] = f2bf(x32[i]);
}

// ---------------- graph prep ----------------

__global__ __launch_bounds__(256) void init_cnt2() {
    int n = blockIdx.x * 256 + threadIdx.x;
    if (n >= N_NODES) return;
    int sc = n / CHW;
#pragma unroll
    for (int c = 0; c < NCH; c++) g_cnt2[n * NCH + c] = (c == sc) ? 1 : 0; // self-loop entry
}

__global__ __launch_bounds__(256) void edge_cnt(const int* __restrict__ eidx) {
    int e = blockIdx.x * 256 + threadIdx.x;
    if (e >= N_EDGES) return;
    int st = g_est;
    int s = eidx[(size_t)e * st];
    int r = eidx[((size_t)N_EDGES + e) * st];
    atomicAdd(&g_cnt2[r * NCH + s / CHW], 1); // fwd entry: dst=r, src=s
    atomicAdd(&g_cnt2[s * NCH + r / CHW], 1); // rev entry: dst=s, src=r
}

// ---------------- exclusive scan over NE2 counts ----------------

__global__ __launch_bounds__(1024) void scan1() {
    __shared__ int sd[1024];
    int i = blockIdx.x * 1024 + threadIdx.x;
    int v = (i < NE2) ? g_cnt2[i] : 0;
    sd[threadIdx.x] = v;
    __syncthreads();
    for (int o = 1; o < 1024; o <<= 1) {
        int tv = (threadIdx.x >= o) ? sd[threadIdx.x - o] : 0;
        __syncthreads();
        sd[threadIdx.x] += tv;
        __syncthreads();
    }
    if (i < NE2) g_offs2[i] = sd[threadIdx.x] - v;
    if (threadIdx.x == 1023) g_bsum[blockIdx.x] = sd[1023];
}

__global__ void scan2(int nb) {
    if (blockIdx.x == 0 && threadIdx.x == 0) {
        int run = 0;
        for (int b = 0; b < nb; b++) {
            g_bbase[b] = run;
            run += g_bsum[b];
        }
        g_offs2[NE2] = CSR_E; // sentinel
    }
}

__global__ __launch_bounds__(256) void scan3() {
    int i = blockIdx.x * 256 + threadIdx.x;
    if (i < NE2) {
        int o = g_offs2[i] + g_bbase[i >> 10];
        g_offs2[i] = o;
        g_cursor2[i] = o;
    }
}

// ---------------- CSR fill: (src, out_w, in_w) bucketed by (dst, src-chunk) ----------------

__global__ __launch_bounds__(256) void fill_edges(const int* __restrict__ eidx,
                                                  const ushort_t* __restrict__ th16,
                                                  const float* __restrict__ th32) {
    int e = blockIdx.x * 256 + threadIdx.x;
    if (e >= N_EDGES) return;
    int st = g_est;
    int s = eidx[(size_t)e * st];
    int r = eidx[((size_t)N_EDGES + e) * st];
    float t = g_is16 ? bf2f(th16[e]) : th32[e];
    float sn, cs_;
    sincosf(t, &sn, &cs_);
    float c2 = cs_ * cs_;
    float s2 = sn * sn;
    // fwd: cs=s, cr=r, out=c2, in=s2
    {
        int p = atomicAdd(&g_cursor2[r * NCH + s / CHW], 1);
        g_csr[p] = make_float4(__int_as_float(s), c2, s2, 0.0f);
    }
    // rev: cs=r, cr=s, out=s2, in=c2
    {
        int p = atomicAdd(&g_cursor2[s * NCH + r / CHW], 1);
        g_csr[p] = make_float4(__int_as_float(r), s2, c2, 0.0f);
    }
}

__global__ __launch_bounds__(256) void fill_self() {
    int n = blockIdx.x * 256 + threadIdx.x;
    if (n >= N_NODES) return;
    int p = atomicAdd(&g_cursor2[n * NCH + n / CHW], 1);
    g_csr[p] = make_float4(__int_as_float(n), 1.0f, 1.0f, 0.0f);
}

// ---------------- degrees from buckets (atomic-free; pairing identity) ----------------
// deg_s[n] = sum of in_w over bucket n; deg_r[n] = sum of out_w over bucket n.

__global__ __launch_bounds__(256) void deg_pass() {
    int n = blockIdx.x * 256 + threadIdx.x;
    if (n >= N_NODES) return;
    int kb = g_offs2[n * NCH];
    int ke = g_offs2[(n + 1) * NCH];
    float ds = 0.f, dr = 0.f;
    for (int k = kb; k < ke; k++) {
        float4 e = g_csr[k];
        ds += e.z; // in_w
        dr += e.y; // out_w
    }
    g_dis_s[n] = rsqrtf(ds + 1e-12f);
    g_dis_r[n] = rsqrtf(dr + 1e-12f);
}

// ---------------- weight packing for MFMA: Bp[kb][n][kk] bf16 ----------------

__global__ __launch_bounds__(256) void prep_wc(const ushort_t* Ws16, const float* Ws32,
                                               const ushort_t* Wd16, const float* Wd32,
                                               const ushort_t* bs16, const float* bs32,
                                               const ushort_t* bd16, const float* bd32,
                                               int layer) {
    ushort_t* Bp = layer ? g_bp2 : g_bp1;
    float* bc = layer ? g_bc2 : g_bc1;
    int is16 = g_is16;
    int i = blockIdx.x * 256 + threadIdx.x;
    if (i < 256 * 128) {
        int k = i >> 7, n = i & 127;
        ushort_t v;
        if (k < 128) {
            int idx = k * 128 + n;
            v = is16 ? Ws16[idx] : f2bf(Ws32[idx]);
        } else {
            int idx = (k - 128) * 128 + n;
            v = is16 ? Wd16[idx] : f2bf(Wd32[idx]);
        }
        int kb = k >> 5, kk = k & 31;
        Bp[((kb * 128 + n) << 5) + kk] = v;
    }
    if (i < 128) {
        float a = is16 ? bf2f(bs16[i]) : bs32[i];
        float b = is16 ? bf2f(bd16[i]) : bd32[i];
        bc[i] = 0.5f * (a + b);
    }
}

__global__ __launch_bounds__(256) void prep_ro(const ushort_t* W16, const float* W32,
                                               const ushort_t* b16, const float* b32) {
    int is16 = g_is16;
    int i = blockIdx.x * 256 + threadIdx.x;
    if (i < 128 * 64) {
        int k = i >> 6, n = i & 63;
        ushort_t v = is16 ? W16[i] : f2bf(W32[i]);
        int kb = k >> 5, kk = k & 31;
        g_bp3[((kb * 64 + n) << 5) + kk] = v;
    }
    if (i < 64) g_bro[i] = is16 ? bf2f(b16[i]) : b32[i];
}

// ---------------- chunk-synchronized aggregation ----------------
// One wave owns 16 consecutive nodes; acc in registers (64 VGPR). All waves
// co-resident (782 blocks <= 4 blocks/CU x 256 CU) sweep src-chunks 0..9 in
// near-lockstep -> instantaneous gather window ~1.3-2.5MB < 4MB per-XCD L2.
// Entry weights applied on the fly: ws=dis_s[src]*out, wd=dis_r[src]*in;
// dst factors 0.5*dis_r[n] / 0.5*dis_s[n] folded into the epilogue.

__global__ __launch_bounds__(256, 4) void aggregate_chunked(const ushort_t* __restrict__ xext, int ext) {
    int wid = (blockIdx.x << 2) | (threadIdx.x >> 6);
    int n0 = wid * 16;
    if (n0 >= N_NODES) return;
    int lane = threadIdx.x & 63;
    const ushort_t* xin = ext ? (g_is16 ? xext : g_xcvt) : g_h1;
    float s0[16], s1[16], d0[16], d1[16];
#pragma unroll
    for (int j = 0; j < 16; j++) { s0[j] = s1[j] = d0[j] = d1[j] = 0.f; }
    for (int c = 0; c < NCH; c++) {
#pragma unroll
        for (int j = 0; j < 16; j++) {
            int base = (n0 + j) * NCH + c;
            int kb = g_offs2[base];
            int ke = g_offs2[base + 1];
            for (int k = kb; k < ke; k++) {
                float4 e = g_csr[k];
                int src = __float_as_int(e.x);
                float ws = g_dis_s[src] * e.y;
                float wd = g_dis_r[src] * e.z;
                uint_t v = *(const uint_t*)(xin + (size_t)src * 128 + lane * 2);
                float x0 = bf2f((ushort_t)(v & 0xffffu));
                float x1 = bf2f((ushort_t)(v >> 16));
                s0[j] = fmaf(ws, x0, s0[j]);
                s1[j] = fmaf(ws, x1, s1[j]);
                d0[j] = fmaf(wd, x0, d0[j]);
                d1[j] = fmaf(wd, x1, d1[j]);
            }
        }
    }
#pragma unroll
    for (int j = 0; j < 16; j++) {
        int n = n0 + j;
        float fs = 0.5f * g_dis_r[n];
        float fd = 0.5f * g_dis_s[n];
        uint_t ps = ((uint_t)f2bf(s1[j] * fs) << 16) | (uint_t)f2bf(s0[j] * fs);
        uint_t pd = ((uint_t)f2bf(d1[j] * fd) << 16) | (uint_t)f2bf(d0[j] * fd);
        *(uint_t*)(g_agg + (size_t)n * 256 + lane * 2) = ps;
        *(uint_t*)(g_agg + (size_t)n * 256 + 128 + lane * 2) = pd;
    }
}

// ---------------- MFMA GEMM: C = act(A[M][K]bf16 @ B + bias) ----------------
// LAYER 0: g_h1 = relu(g_agg @ g_bp1 + g_bc1), K=256, N=128
// LAYER 1: g_h2 = relu(g_agg @ g_bp2 + g_bc2), K=256, N=128
// LAYER 2: out  = g_h2 @ g_bp3 + g_bro, K=128, N=64 (dtype-flex store to outp)
// Verified layouts: A[m=lane&15][k=(lane>>4)*8+j]; B[k=(lane>>4)*8+j][n=lane&15];
//                   C col=lane&15, row=(lane>>4)*4+reg.

template <int LAYER, int KB, int NN, int NT, int RELU>
__global__ __launch_bounds__(256) void gemm_mfma(void* __restrict__ outp) {
    const ushort_t* A = (LAYER == 2) ? g_h2 : g_agg;
    const ushort_t* Bp = (LAYER == 0) ? g_bp1 : (LAYER == 1) ? g_bp2 : g_bp3;
    const float* bias = (LAYER == 0) ? g_bc1 : (LAYER == 1) ? g_bc2 : g_bro;
    const int M = N_NODES;
    const int K = KB * 32;
    int w = threadIdx.x >> 6; // wave 0..3
    int lane = threadIdx.x & 63;
    int c = lane & 15;
    int q = lane >> 4;
    int mBase = blockIdx.x * 64 + w * 16;

    f32x4 acc[NT];
#pragma unroll
    for (int nt = 0; nt < NT; nt++) acc[nt] = {0.f, 0.f, 0.f, 0.f};

    int arow = mBase + c;
    if (arow >= M) arow = M - 1; // clamp; stores guarded

#pragma unroll
    for (int kb = 0; kb < KB; kb++) {
        bf16x8 a = *(const bf16x8*)(A + (size_t)arow * K + kb * 32 + q * 8);
#pragma unroll
        for (int nt = 0; nt < NT; nt++) {
            bf16x8 b = *(const bf16x8*)(Bp + (((kb * NN + nt * 16 + c) << 5) + q * 8));
            acc[nt] = __builtin_amdgcn_mfma_f32_16x16x32_bf16(a, b, acc[nt], 0, 0, 0);
        }
    }

    int is16 = (LAYER == 2) ? g_is16 : 1;
#pragma unroll
    for (int nt = 0; nt < NT; nt++) {
        int n = nt * 16 + c;
        float bi = bias[n];
#pragma unroll
        for (int r = 0; r < 4; r++) {
            int m = mBase + q * 4 + r;
            if (m >= M) continue;
            float v = acc[nt][r] + bi;
            if (RELU) v = fmaxf(v, 0.f);
            if (LAYER == 0)
                g_h1[(size_t)m * NN + n] = f2bf(v);
            else if (LAYER == 1)
                g_h2[(size_t)m * NN + n] = f2bf(v);
            else if (is16)
                ((ushort_t*)outp)[(size_t)m * NN + n] = f2bf(v);
            else
                ((float*)outp)[(size_t)m * NN + n] = v;
        }
    }
}

// ---------------- launch ----------------

static inline int cdiv(int a, int b) { return (a + b - 1) / b; }

extern "C" void kernel_launch(void* const* d_in, const int* in_sizes, int n_in,
                              void* d_out, int out_size, void* d_ws, size_t ws_size,
                              hipStream_t stream) {
    const void* x = d_in[0]; // [50000][128]
    const int* eidx = (const int*)d_in[1];
    const void* theta = d_in[2];
    const void* W1s = d_in[3];
    const void* W1d = d_in[4];
    const void* b1s = d_in[5];
    const void* b1d = d_in[6];
    const void* W2s = d_in[7];
    const void* W2d = d_in[8];
    const void* b2s = d_in[9];
    const void* b2d = d_in[10];
    const void* Wro = d_in[11];
    const void* bro = d_in[12];
    (void)in_sizes; (void)n_in; (void)out_size; (void)d_ws; (void)ws_size;

    const int NB2 = cdiv(NE2, 1024); // 489

    detect_kernel<<<1, 64, 0, stream>>>((const uint_t*)x, eidx);
    conv_x<<<cdiv(N_NODES * 128, 256), 256, 0, stream>>>((const float*)x);
    init_cnt2<<<cdiv(N_NODES, 256), 256, 0, stream>>>();
    edge_cnt<<<cdiv(N_EDGES, 256), 256, 0, stream>>>(eidx);
    scan1<<<NB2, 1024, 0, stream>>>();
    scan2<<<1, 1, 0, stream>>>(NB2);
    scan3<<<cdiv(NE2, 256), 256, 0, stream>>>();
    fill_edges<<<cdiv(N_EDGES, 256), 256, 0, stream>>>(eidx, (const ushort_t*)theta, (const float*)theta);
    fill_self<<<cdiv(N_NODES, 256), 256, 0, stream>>>();
    deg_pass<<<cdiv(N_NODES, 256), 256, 0, stream>>>();
    prep_wc<<<cdiv(256 * 128, 256), 256, 0, stream>>>((const ushort_t*)W1s, (const float*)W1s,
                                                      (const ushort_t*)W1d, (const float*)W1d,
                                                      (const ushort_t*)b1s, (const float*)b1s,
                                                      (const ushort_t*)b1d, (const float*)b1d, 0);
    prep_wc<<<cdiv(256 * 128, 256), 256, 0, stream>>>((const ushort_t*)W2s, (const float*)W2s,
                                                      (const ushort_t*)W2d, (const float*)W2d,
                                                      (const ushort_t*)b2s, (const float*)b2s,
                                                      (const ushort_t*)b2d, (const float*)b2d, 1);
    prep_ro<<<cdiv(128 * 64, 256), 256, 0, stream>>>((const ushort_t*)Wro, (const float*)Wro,
                                                     (const ushort_t*)bro, (const float*)bro);

    const int AB = cdiv(N_NODES, 64); // 782 blocks, 16 nodes/wave
    const int GB = cdiv(N_NODES, 64); // 782
    // layer 1
    aggregate_chunked<<<AB, 256, 0, stream>>>((const ushort_t*)x, 1);
    gemm_mfma<0, 8, 128, 8, 1><<<GB, 256, 0, stream>>>(nullptr);
    // layer 2
    aggregate_chunked<<<AB, 256, 0, stream>>>(nullptr, 0);
    gemm_mfma<1, 8, 128, 8, 1><<<GB, 256, 0, stream>>>(nullptr);
    // readout
    gemm_mfma<2, 4, 64, 4, 0><<<GB, 256, 0, stream>>>(d_out);
}

// Round 8
// 486.475 us; speedup vs baseline: 1.4697x; 1.4697x over previous
//
#include <hip/hip_runtime.h>

#define N_NODES 50000
#define N_EDGES 400000
#define CSR_E (2 * N_EDGES + N_NODES) /* 850000 */
#define NCH 10        /* source chunks */
#define CHW 5000      /* chunk width: 5000 nodes * 256B = 1.28MB window */
#define NG 3125       /* node groups of 16 */
#define NE2 (NG * NCH * 16) /* 500000 buckets: (group, chunk, j) */

typedef unsigned short ushort_t;
typedef unsigned int uint_t;
typedef __attribute__((ext_vector_type(8))) short bf16x8;
typedef __attribute__((ext_vector_type(4))) float f32x4;

__device__ __forceinline__ float bf2f(ushort_t u) {
    return __uint_as_float(((uint_t)u) << 16);
}
__device__ __forceinline__ ushort_t f2bf(float f) {
    uint_t b = __float_as_uint(f);
    b += 0x7FFFu + ((b >> 16) & 1u); // RNE
    return (ushort_t)(b >> 16);
}
// bucket index: group-major, then chunk, then node-within-group
__device__ __forceinline__ int bidx(int n, int c) {
    return ((n >> 4) * (NCH * 16)) + (c << 4) + (n & 15);
}

// ---------------- static device scratch (module BSS; d_ws untouched) ----------------
// NOTE: only reference these from device code (host sees shadow addresses - r4 fault).

__device__ int g_est;  // edge-index word stride: 1 = int32, 2 = int64
__device__ int g_is16; // 1 = float tensors bf16-packed, 0 = fp32
__device__ float g_dis_s[N_NODES];
__device__ float g_dis_r[N_NODES];
__device__ int g_cnt2[NE2];
__device__ int g_offs2[NE2 + 1];
__device__ int g_cursor2[NE2];
__device__ int g_bsum[512];
__device__ int g_bbase[512];
__device__ __align__(16) float4 g_csr[CSR_E]; // (src, out|wS, in|wD, dst)
__device__ __align__(16) ushort_t g_agg[(size_t)N_NODES * 256]; // bf16 [N][s128|d128]
__device__ __align__(16) ushort_t g_h1[(size_t)N_NODES * 128];  // bf16
__device__ __align__(16) ushort_t g_h2[(size_t)N_NODES * 128];  // bf16
__device__ __align__(16) ushort_t g_xcvt[(size_t)N_NODES * 128]; // bf16 (fp32-input fallback)
__device__ __align__(16) ushort_t g_bp1[8 * 128 * 32]; // B packed [kb][n][kk] bf16
__device__ __align__(16) ushort_t g_bp2[8 * 128 * 32];
__device__ __align__(16) ushort_t g_bp3[4 * 64 * 32];
__device__ float g_bc1[128];
__device__ float g_bc2[128];
__device__ float g_bro[64];

// ---------------- dtype / index-width detection ----------------

__global__ void detect_kernel(const uint_t* __restrict__ xw, const int* __restrict__ eidx) {
    if (threadIdx.x == 0 && blockIdx.x == 0) {
        int cnt = 0;
        for (int i = 0; i < 64; i++) {
            uint_t w = xw[i];
            int elo = (w >> 7) & 0xFF;
            if (elo >= 100 && elo <= 150) cnt++;
        }
        g_is16 = (cnt >= 48) ? 1 : 0;
        int any = 0;
        for (int i = 1; i < 128; i += 2) any |= eidx[i];
        g_est = any ? 1 : 2;
    }
}

// fp32-input fallback: convert x to bf16 once (no-op when already bf16)
__global__ __launch_bounds__(256) void conv_x(const float* __restrict__ x32) {
    if (g_is16) return;
    int t = blockIdx.x * 256 + threadIdx.x; // 800000 threads, 8 elems each
    if (t >= N_NODES * 128 / 8) return;
    const float4* p = (const float4*)(x32 + t * 8);
    float4 a = p[0], b = p[1];
    ushort4 o0, o1;
    o0.x = f2bf(a.x); o0.y = f2bf(a.y); o0.z = f2bf(a.z); o0.w = f2bf(a.w);
    o1.x = f2bf(b.x); o1.y = f2bf(b.y); o1.z = f2bf(b.z); o1.w = f2bf(b.w);
    *(ushort4*)(g_xcvt + t * 8) = o0;
    *(ushort4*)(g_xcvt + t * 8 + 4) = o1;
}

// ---------------- graph prep ----------------

__global__ __launch_bounds__(256) void init_cnt2() {
    int n = blockIdx.x * 256 + threadIdx.x;
    if (n >= N_NODES) return;
    int sc = n / CHW;
#pragma unroll
    for (int c = 0; c < NCH; c++) g_cnt2[bidx(n, c)] = (c == sc) ? 1 : 0; // self-loop entry
}

__global__ __launch_bounds__(256) void edge_cnt(const int* __restrict__ eidx) {
    int e = blockIdx.x * 256 + threadIdx.x;
    if (e >= N_EDGES) return;
    int st = g_est;
    int s = eidx[(size_t)e * st];
    int r = eidx[((size_t)N_EDGES + e) * st];
    atomicAdd(&g_cnt2[bidx(r, s / CHW)], 1); // fwd: dst=r, src-chunk of s
    atomicAdd(&g_cnt2[bidx(s, r / CHW)], 1); // rev: dst=s, src-chunk of r
}

// ---------------- exclusive scan over NE2 counts ----------------

__global__ __launch_bounds__(1024) void scan1() {
    __shared__ int sd[1024];
    int i = blockIdx.x * 1024 + threadIdx.x;
    int v = (i < NE2) ? g_cnt2[i] : 0;
    sd[threadIdx.x] = v;
    __syncthreads();
    for (int o = 1; o < 1024; o <<= 1) {
        int tv = (threadIdx.x >= o) ? sd[threadIdx.x - o] : 0;
        __syncthreads();
        sd[threadIdx.x] += tv;
        __syncthreads();
    }
    if (i < NE2) g_offs2[i] = sd[threadIdx.x] - v;
    if (threadIdx.x == 1023) g_bsum[blockIdx.x] = sd[1023];
}

__global__ void scan2(int nb) {
    if (blockIdx.x == 0 && threadIdx.x == 0) {
        int run = 0;
        for (int b = 0; b < nb; b++) {
            g_bbase[b] = run;
            run += g_bsum[b];
        }
        g_offs2[NE2] = CSR_E; // sentinel
    }
}

__global__ __launch_bounds__(256) void scan3() {
    int i = blockIdx.x * 256 + threadIdx.x;
    if (i < NE2) {
        int o = g_offs2[i] + g_bbase[i >> 10];
        g_offs2[i] = o;
        g_cursor2[i] = o;
    }
}

// ---------------- CSR fill: (src, out_w, in_w, dst); edges + self merged ----------------

__global__ __launch_bounds__(256) void fill_all(const int* __restrict__ eidx,
                                                const ushort_t* __restrict__ th16,
                                                const float* __restrict__ th32) {
    int e = blockIdx.x * 256 + threadIdx.x;
    if (e < N_EDGES) {
        int st = g_est;
        int s = eidx[(size_t)e * st];
        int r = eidx[((size_t)N_EDGES + e) * st];
        float t = g_is16 ? bf2f(th16[e]) : th32[e];
        float sn, cs_;
        sincosf(t, &sn, &cs_);
        float c2 = cs_ * cs_;
        float s2 = sn * sn;
        // fwd: cs=s, cr=r, out=c2, in=s2
        {
            int p = atomicAdd(&g_cursor2[bidx(r, s / CHW)], 1);
            g_csr[p] = make_float4(__int_as_float(s), c2, s2, __int_as_float(r));
        }
        // rev: cs=r, cr=s, out=s2, in=c2
        {
            int p = atomicAdd(&g_cursor2[bidx(s, r / CHW)], 1);
            g_csr[p] = make_float4(__int_as_float(r), s2, c2, __int_as_float(s));
        }
    }
    if (e < N_NODES) {
        int p = atomicAdd(&g_cursor2[bidx(e, e / CHW)], 1);
        g_csr[p] = make_float4(__int_as_float(e), 1.0f, 1.0f, __int_as_float(e));
    }
}

// ---------------- degrees from buckets (atomic-free; pairing identity) ----------------
// deg_s[n] = sum of in_w over node-n entries; deg_r[n] = sum of out_w.

__global__ __launch_bounds__(256) void deg_pass() {
    int n = blockIdx.x * 256 + threadIdx.x;
    if (n >= N_NODES) return;
    float ds = 0.f, dr = 0.f;
#pragma unroll
    for (int c = 0; c < NCH; c++) {
        int idx = bidx(n, c);
        int kb = g_offs2[idx];
        int ke = g_offs2[idx + 1];
        for (int k = kb; k < ke; k++) {
            float4 e = g_csr[k];
            ds += e.z; // in_w
            dr += e.y; // out_w
        }
    }
    g_dis_s[n] = rsqrtf(ds + 1e-12f);
    g_dis_r[n] = rsqrtf(dr + 1e-12f);
}

// ---------------- finalize: fold ALL factors (src dis, dst dis, ALPHA) ----------------

__global__ __launch_bounds__(256) void finalize_w() {
    int i = blockIdx.x * 256 + threadIdx.x;
    if (i >= CSR_E) return;
    float4 e = g_csr[i];
    int m = __float_as_int(e.x); // src (cs)
    int n = __float_as_int(e.w); // dst (cr)
    float wS = 0.5f * g_dis_s[m] * e.y * g_dis_r[n];
    float wD = 0.5f * g_dis_r[m] * e.z * g_dis_s[n];
    g_csr[i] = make_float4(e.x, wS, wD, e.w);
}

// ---------------- weight prep (merged): Bp[kb][n][kk] bf16 + biases ----------------

__global__ __launch_bounds__(256) void prep_all(const ushort_t* W1s16, const float* W1s32,
                                                const ushort_t* W1d16, const float* W1d32,
                                                const ushort_t* b1s16, const float* b1s32,
                                                const ushort_t* b1d16, const float* b1d32,
                                                const ushort_t* W2s16, const float* W2s32,
                                                const ushort_t* W2d16, const float* W2d32,
                                                const ushort_t* b2s16, const float* b2s32,
                                                const ushort_t* b2d16, const float* b2d32,
                                                const ushort_t* Wro16, const float* Wro32,
                                                const ushort_t* bro16, const float* bro32) {
    int is16 = g_is16;
    int t = blockIdx.x * 256 + threadIdx.x;
    if (t < 2 * 32768) { // hidden layers
        int layer = t >> 15;
        int i = t & 32767;
        const ushort_t* Ws16 = layer ? W2s16 : W1s16;
        const float* Ws32 = layer ? W2s32 : W1s32;
        const ushort_t* Wd16 = layer ? W2d16 : W1d16;
        const float* Wd32 = layer ? W2d32 : W1d32;
        ushort_t* Bp = layer ? g_bp2 : g_bp1;
        int k = i >> 7, n = i & 127;
        ushort_t v;
        if (k < 128) {
            int idx = k * 128 + n;
            v = is16 ? Ws16[idx] : f2bf(Ws32[idx]);
        } else {
            int idx = (k - 128) * 128 + n;
            v = is16 ? Wd16[idx] : f2bf(Wd32[idx]);
        }
        int kb = k >> 5, kk = k & 31;
        Bp[((kb * 128 + n) << 5) + kk] = v;
        if (i < 128) {
            const ushort_t* bs16 = layer ? b2s16 : b1s16;
            const float* bs32 = layer ? b2s32 : b1s32;
            const ushort_t* bd16 = layer ? b2d16 : b1d16;
            const float* bd32 = layer ? b2d32 : b1d32;
            float a = is16 ? bf2f(bs16[i]) : bs32[i];
            float b = is16 ? bf2f(bd16[i]) : bd32[i];
            (layer ? g_bc2 : g_bc1)[i] = 0.5f * (a + b);
        }
    } else if (t < 2 * 32768 + 8192) { // readout
        int i = t - 2 * 32768;
        int k = i >> 6, n = i & 63;
        ushort_t v = is16 ? Wro16[i] : f2bf(Wro32[i]);
        int kb = k >> 5, kk = k & 31;
        g_bp3[((kb * 64 + n) << 5) + kk] = v;
        if (i < 64) g_bro[i] = is16 ? bf2f(bro16[i]) : bro32[i];
    }
}

// ---------------- aggregation: flat-range, LDS accumulators, unroll x8 ----------------
// One wave owns 16 nodes = one contiguous CSR range (group-major, chunk-ordered
// inside -> co-resident waves sweep src-chunks in soft lockstep, keeping the
// instantaneous gather window ~L2-sized). All weights pre-folded (finalize_w),
// so the hot chain is csr[k] -> x[src] only, 8 in flight. Accumulators live in
// LDS [16][128]x2ch fp32 (dynamic j without register spill; 2-way bank aliasing
// is free). 64KB/block -> 2 blocks/CU, 8 waves/CU; MLP 8 x 2048 waves.

__global__ __launch_bounds__(256, 2) void aggregate_lds(const ushort_t* __restrict__ xext, int ext) {
    __shared__ float lds[4][2][2048]; // [wave][ch][16*128] = 64 KB
    int w = threadIdx.x >> 6;
    int lane = threadIdx.x & 63;
    int g = (blockIdx.x << 2) | w;
    float* accS = lds[w][0];
    float* accD = lds[w][1];
#pragma unroll
    for (int j = 0; j < 16; j++) { // wave-private zero; no barrier needed
        *(float2*)(accS + j * 128 + lane * 2) = make_float2(0.f, 0.f);
        *(float2*)(accD + j * 128 + lane * 2) = make_float2(0.f, 0.f);
    }
    if (g >= NG) return;
    const ushort_t* xin = ext ? (g_is16 ? xext : g_xcvt) : g_h1;
    int ks = g_offs2[g * 160];
    int ke = g_offs2[g * 160 + 160];
    int k = ks;
    for (; k + 8 <= ke; k += 8) {
        float4 e[8];
#pragma unroll
        for (int i = 0; i < 8; i++) e[i] = g_csr[k + i];
        uint_t v[8];
#pragma unroll
        for (int i = 0; i < 8; i++)
            v[i] = *(const uint_t*)(xin + (size_t)__float_as_int(e[i].x) * 128 + lane * 2);
#pragma unroll
        for (int i = 0; i < 8; i++) {
            int j = __float_as_int(e[i].w) & 15;
            float x0 = bf2f((ushort_t)(v[i] & 0xffffu));
            float x1 = bf2f((ushort_t)(v[i] >> 16));
            float* pS = accS + j * 128 + lane * 2;
            float2 a = *(float2*)pS;
            a.x = fmaf(e[i].y, x0, a.x);
            a.y = fmaf(e[i].y, x1, a.y);
            *(float2*)pS = a;
            float* pD = accD + j * 128 + lane * 2;
            float2 b = *(float2*)pD;
            b.x = fmaf(e[i].z, x0, b.x);
            b.y = fmaf(e[i].z, x1, b.y);
            *(float2*)pD = b;
        }
    }
    for (; k < ke; k++) {
        float4 e = g_csr[k];
        uint_t v = *(const uint_t*)(xin + (size_t)__float_as_int(e.x) * 128 + lane * 2);
        int j = __float_as_int(e.w) & 15;
        float x0 = bf2f((ushort_t)(v & 0xffffu));
        float x1 = bf2f((ushort_t)(v >> 16));
        float* pS = accS + j * 128 + lane * 2;
        float2 a = *(float2*)pS;
        a.x = fmaf(e.y, x0, a.x);
        a.y = fmaf(e.y, x1, a.y);
        *(float2*)pS = a;
        float* pD = accD + j * 128 + lane * 2;
        float2 b = *(float2*)pD;
        b.x = fmaf(e.z, x0, b.x);
        b.y = fmaf(e.z, x1, b.y);
        *(float2*)pD = b;
    }
#pragma unroll
    for (int j = 0; j < 16; j++) {
        int n = (g << 4) | j;
        float2 a = *(float2*)(accS + j * 128 + lane * 2);
        float2 b = *(float2*)(accD + j * 128 + lane * 2);
        uint_t ps = ((uint_t)f2bf(a.y) << 16) | (uint_t)f2bf(a.x);
        uint_t pd = ((uint_t)f2bf(b.y) << 16) | (uint_t)f2bf(b.x);
        *(uint_t*)(g_agg + (size_t)n * 256 + lane * 2) = ps;
        *(uint_t*)(g_agg + (size_t)n * 256 + 128 + lane * 2) = pd;
    }
}

// ---------------- MFMA GEMM: C = act(A[M][K]bf16 @ B + bias) ----------------
// LAYER 0: g_h1 = relu(g_agg @ g_bp1 + g_bc1), K=256, N=128
// LAYER 1: g_h2 = relu(g_agg @ g_bp2 + g_bc2), K=256, N=128
// LAYER 2: out  = g_h2 @ g_bp3 + g_bro, K=128, N=64 (dtype-flex store to outp)
// Verified layouts: A[m=lane&15][k=(lane>>4)*8+j]; B[k=(lane>>4)*8+j][n=lane&15];
//                   C col=lane&15, row=(lane>>4)*4+reg.

template <int LAYER, int KB, int NN, int NT, int RELU>
__global__ __launch_bounds__(256) void gemm_mfma(void* __restrict__ outp) {
    const ushort_t* A = (LAYER == 2) ? g_h2 : g_agg;
    const ushort_t* Bp = (LAYER == 0) ? g_bp1 : (LAYER == 1) ? g_bp2 : g_bp3;
    const float* bias = (LAYER == 0) ? g_bc1 : (LAYER == 1) ? g_bc2 : g_bro;
    const int M = N_NODES;
    const int K = KB * 32;
    int w = threadIdx.x >> 6; // wave 0..3
    int lane = threadIdx.x & 63;
    int c = lane & 15;
    int q = lane >> 4;
    int mBase = blockIdx.x * 64 + w * 16;

    f32x4 acc[NT];
#pragma unroll
    for (int nt = 0; nt < NT; nt++) acc[nt] = {0.f, 0.f, 0.f, 0.f};

    int arow = mBase + c;
    if (arow >= M) arow = M - 1; // clamp; stores guarded

#pragma unroll
    for (int kb = 0; kb < KB; kb++) {
        bf16x8 a = *(const bf16x8*)(A + (size_t)arow * K + kb * 32 + q * 8);
#pragma unroll
        for (int nt = 0; nt < NT; nt++) {
            bf16x8 b = *(const bf16x8*)(Bp + (((kb * NN + nt * 16 + c) << 5) + q * 8));
            acc[nt] = __builtin_amdgcn_mfma_f32_16x16x32_bf16(a, b, acc[nt], 0, 0, 0);
        }
    }

    int is16 = (LAYER == 2) ? g_is16 : 1;
#pragma unroll
    for (int nt = 0; nt < NT; nt++) {
        int n = nt * 16 + c;
        float bi = bias[n];
#pragma unroll
        for (int r = 0; r < 4; r++) {
            int m = mBase + q * 4 + r;
            if (m >= M) continue;
            float v = acc[nt][r] + bi;
            if (RELU) v = fmaxf(v, 0.f);
            if (LAYER == 0)
                g_h1[(size_t)m * NN + n] = f2bf(v);
            else if (LAYER == 1)
                g_h2[(size_t)m * NN + n] = f2bf(v);
            else if (is16)
                ((ushort_t*)outp)[(size_t)m * NN + n] = f2bf(v);
            else
                ((float*)outp)[(size_t)m * NN + n] = v;
        }
    }
}

// ---------------- launch ----------------

static inline int cdiv(int a, int b) { return (a + b - 1) / b; }

extern "C" void kernel_launch(void* const* d_in, const int* in_sizes, int n_in,
                              void* d_out, int out_size, void* d_ws, size_t ws_size,
                              hipStream_t stream) {
    const void* x = d_in[0]; // [50000][128]
    const int* eidx = (const int*)d_in[1];
    const void* theta = d_in[2];
    const void* W1s = d_in[3];
    const void* W1d = d_in[4];
    const void* b1s = d_in[5];
    const void* b1d = d_in[6];
    const void* W2s = d_in[7];
    const void* W2d = d_in[8];
    const void* b2s = d_in[9];
    const void* b2d = d_in[10];
    const void* Wro = d_in[11];
    const void* bro = d_in[12];
    (void)in_sizes; (void)n_in; (void)out_size; (void)d_ws; (void)ws_size;

    const int NB2 = cdiv(NE2, 1024); // 489

    detect_kernel<<<1, 64, 0, stream>>>((const uint_t*)x, eidx);
    conv_x<<<cdiv(N_NODES * 128 / 8, 256), 256, 0, stream>>>((const float*)x);
    init_cnt2<<<cdiv(N_NODES, 256), 256, 0, stream>>>();
    edge_cnt<<<cdiv(N_EDGES, 256), 256, 0, stream>>>(eidx);
    scan1<<<NB2, 1024, 0, stream>>>();
    scan2<<<1, 1, 0, stream>>>(NB2);
    scan3<<<cdiv(NE2, 256), 256, 0, stream>>>();
    fill_all<<<cdiv(N_EDGES, 256), 256, 0, stream>>>(eidx, (const ushort_t*)theta, (const float*)theta);
    deg_pass<<<cdiv(N_NODES, 256), 256, 0, stream>>>();
    finalize_w<<<cdiv(CSR_E, 256), 256, 0, stream>>>();
    prep_all<<<cdiv(2 * 32768 + 8192, 256), 256, 0, stream>>>(
        (const ushort_t*)W1s, (const float*)W1s, (const ushort_t*)W1d, (const float*)W1d,
        (const ushort_t*)b1s, (const float*)b1s, (const ushort_t*)b1d, (const float*)b1d,
        (const ushort_t*)W2s, (const float*)W2s, (const ushort_t*)W2d, (const float*)W2d,
        (const ushort_t*)b2s, (const float*)b2s, (const ushort_t*)b2d, (const float*)b2d,
        (const ushort_t*)Wro, (const float*)Wro, (const ushort_t*)bro, (const float*)bro);

    const int AB = cdiv(NG, 4); // 782
    const int GB = cdiv(N_NODES, 64); // 782
    // layer 1
    aggregate_lds<<<AB, 256, 0, stream>>>((const ushort_t*)x, 1);
    gemm_mfma<0, 8, 128, 8, 1><<<GB, 256, 0, stream>>>(nullptr);
    // layer 2
    aggregate_lds<<<AB, 256, 0, stream>>>(nullptr, 0);
    gemm_mfma<1, 8, 128, 8, 1><<<GB, 256, 0, stream>>>(nullptr);
    // readout
    gemm_mfma<2, 4, 64, 4, 0><<<GB, 256, 0, stream>>>(d_out);
}

// Round 9
// 386.480 us; speedup vs baseline: 1.8500x; 1.2587x over previous
//
#include <hip/hip_runtime.h>

#define N_NODES 50000
#define N_EDGES 400000
#define CSR_E (2 * N_EDGES + N_NODES) /* 850000 */
#define NCH 10        /* source chunks */
#define CHW 5000      /* chunk width: 5000 nodes * 256B = 1.28MB window */
#define NE2 (N_NODES * NCH) /* buckets: (node, chunk), node-major contiguous */

typedef unsigned short ushort_t;
typedef unsigned int uint_t;
typedef __attribute__((ext_vector_type(8))) short bf16x8;
typedef __attribute__((ext_vector_type(4))) float f32x4;

__device__ __forceinline__ float bf2f(ushort_t u) {
    return __uint_as_float(((uint_t)u) << 16);
}
__device__ __forceinline__ ushort_t f2bf(float f) {
    uint_t b = __float_as_uint(f);
    b += 0x7FFFu + ((b >> 16) & 1u); // RNE
    return (ushort_t)(b >> 16);
}

// ---------------- static device scratch (module BSS; d_ws untouched) ----------------
// NOTE: only reference these from device code (host sees shadow addresses - r4 fault).

__device__ int g_est;  // edge-index word stride: 1 = int32, 2 = int64
__device__ int g_is16; // 1 = float tensors bf16-packed, 0 = fp32
__device__ float g_dis_s[N_NODES];
__device__ float g_dis_r[N_NODES];
__device__ int g_cnt2[NE2];
__device__ int g_offs2[NE2 + 1];
__device__ int g_cursor2[NE2];
__device__ int g_bsum[512];
__device__ int g_bbase[512];
__device__ __align__(16) float4 g_csr[CSR_E]; // raw (src,out,in,dst) -> final (src,wS,wD,dst)
__device__ __align__(16) ushort_t g_agg[(size_t)N_NODES * 256]; // bf16 [N][s128|d128]
__device__ __align__(16) ushort_t g_h1[(size_t)N_NODES * 128];  // bf16
__device__ __align__(16) ushort_t g_h2[(size_t)N_NODES * 128];  // bf16
__device__ __align__(16) ushort_t g_xcvt[(size_t)N_NODES * 128]; // bf16 (fp32-input fallback)
__device__ __align__(16) ushort_t g_bp1[8 * 128 * 32]; // B packed [kb][n][kk] bf16
__device__ __align__(16) ushort_t g_bp2[8 * 128 * 32];
__device__ __align__(16) ushort_t g_bp3[4 * 64 * 32];
__device__ float g_bc1[128];
__device__ float g_bc2[128];
__device__ float g_bro[64];

// ---------------- dtype / index-width detection ----------------

__global__ void detect_kernel(const uint_t* __restrict__ xw, const int* __restrict__ eidx) {
    if (threadIdx.x == 0 && blockIdx.x == 0) {
        int cnt = 0;
        for (int i = 0; i < 64; i++) {
            uint_t w = xw[i];
            int elo = (w >> 7) & 0xFF;
            if (elo >= 100 && elo <= 150) cnt++;
        }
        g_is16 = (cnt >= 48) ? 1 : 0;
        int any = 0;
        for (int i = 1; i < 128; i += 2) any |= eidx[i];
        g_est = any ? 1 : 2;
    }
}

// fp32-input fallback: convert x to bf16 once (no-op when already bf16)
__global__ __launch_bounds__(256) void conv_x(const float* __restrict__ x32) {
    if (g_is16) return;
    int t = blockIdx.x * 256 + threadIdx.x;
    if (t >= N_NODES * 128 / 8) return;
    const float4* p = (const float4*)(x32 + t * 8);
    float4 a = p[0], b = p[1];
    ushort4 o0, o1;
    o0.x = f2bf(a.x); o0.y = f2bf(a.y); o0.z = f2bf(a.z); o0.w = f2bf(a.w);
    o1.x = f2bf(b.x); o1.y = f2bf(b.y); o1.z = f2bf(b.z); o1.w = f2bf(b.w);
    *(ushort4*)(g_xcvt + t * 8) = o0;
    *(ushort4*)(g_xcvt + t * 8 + 4) = o1;
}

// ---------------- graph prep ----------------

__global__ __launch_bounds__(256) void init_cnt2() {
    int n = blockIdx.x * 256 + threadIdx.x;
    if (n >= N_NODES) return;
    int sc = n / CHW;
#pragma unroll
    for (int c = 0; c < NCH; c++) g_cnt2[n * NCH + c] = (c == sc) ? 1 : 0; // self-loop entry
}

__global__ __launch_bounds__(256) void edge_cnt(const int* __restrict__ eidx) {
    int e = blockIdx.x * 256 + threadIdx.x;
    if (e >= N_EDGES) return;
    int st = g_est;
    int s = eidx[(size_t)e * st];
    int r = eidx[((size_t)N_EDGES + e) * st];
    atomicAdd(&g_cnt2[r * NCH + s / CHW], 1); // fwd: dst=r, src-chunk of s
    atomicAdd(&g_cnt2[s * NCH + r / CHW], 1); // rev: dst=s, src-chunk of r
}

// ---------------- exclusive scan over NE2 counts ----------------

__global__ __launch_bounds__(1024) void scan1() {
    __shared__ int sd[1024];
    int i = blockIdx.x * 1024 + threadIdx.x;
    int v = (i < NE2) ? g_cnt2[i] : 0;
    sd[threadIdx.x] = v;
    __syncthreads();
    for (int o = 1; o < 1024; o <<= 1) {
        int tv = (threadIdx.x >= o) ? sd[threadIdx.x - o] : 0;
        __syncthreads();
        sd[threadIdx.x] += tv;
        __syncthreads();
    }
    if (i < NE2) g_offs2[i] = sd[threadIdx.x] - v;
    if (threadIdx.x == 1023) g_bsum[blockIdx.x] = sd[1023];
}

__global__ void scan2(int nb) {
    if (blockIdx.x == 0 && threadIdx.x == 0) {
        int run = 0;
        for (int b = 0; b < nb; b++) {
            g_bbase[b] = run;
            run += g_bsum[b];
        }
        g_offs2[NE2] = CSR_E; // sentinel
    }
}

__global__ __launch_bounds__(256) void scan3() {
    int i = blockIdx.x * 256 + threadIdx.x;
    if (i < NE2) {
        int o = g_offs2[i] + g_bbase[i >> 10];
        g_offs2[i] = o;
        g_cursor2[i] = o;
    }
}

// ---------------- CSR fill: (src, out_w, in_w, dst); edges + self merged ----------------

__global__ __launch_bounds__(256) void fill_all(const int* __restrict__ eidx,
                                                const ushort_t* __restrict__ th16,
                                                const float* __restrict__ th32) {
    int e = blockIdx.x * 256 + threadIdx.x;
    if (e < N_EDGES) {
        int st = g_est;
        int s = eidx[(size_t)e * st];
        int r = eidx[((size_t)N_EDGES + e) * st];
        float t = g_is16 ? bf2f(th16[e]) : th32[e];
        float sn, cs_;
        sincosf(t, &sn, &cs_);
        float c2 = cs_ * cs_;
        float s2 = sn * sn;
        // fwd: cs=s, cr=r, out=c2, in=s2
        {
            int p = atomicAdd(&g_cursor2[r * NCH + s / CHW], 1);
            g_csr[p] = make_float4(__int_as_float(s), c2, s2, __int_as_float(r));
        }
        // rev: cs=r, cr=s, out=s2, in=c2
        {
            int p = atomicAdd(&g_cursor2[s * NCH + r / CHW], 1);
            g_csr[p] = make_float4(__int_as_float(r), s2, c2, __int_as_float(s));
        }
    }
    if (e < N_NODES) {
        int p = atomicAdd(&g_cursor2[e * NCH + e / CHW], 1);
        g_csr[p] = make_float4(__int_as_float(e), 1.0f, 1.0f, __int_as_float(e));
    }
}

// ---------------- degrees from buckets (atomic-free; pairing identity) ----------------
// deg_s[n] = sum of in_w over node-n entries; deg_r[n] = sum of out_w.

__global__ __launch_bounds__(256) void deg_pass() {
    int n = blockIdx.x * 256 + threadIdx.x;
    if (n >= N_NODES) return;
    int kb = g_offs2[n * NCH];
    int ke = g_offs2[n * NCH + NCH];
    float ds = 0.f, dr = 0.f;
    for (int k = kb; k < ke; k++) {
        float4 e = g_csr[k];
        ds += e.z; // in_w
        dr += e.y; // out_w
    }
    g_dis_s[n] = rsqrtf(ds + 1e-12f);
    g_dis_r[n] = rsqrtf(dr + 1e-12f);
}

// ---------------- finalize: fold ALL factors (src dis, dst dis, ALPHA) ----------------

__global__ __launch_bounds__(256) void finalize_w() {
    int i = blockIdx.x * 256 + threadIdx.x;
    if (i >= CSR_E) return;
    float4 e = g_csr[i];
    int m = __float_as_int(e.x); // src (cs)
    int n = __float_as_int(e.w); // dst (cr)
    float wS = 0.5f * g_dis_s[m] * e.y * g_dis_r[n];
    float wD = 0.5f * g_dis_r[m] * e.z * g_dis_s[n];
    g_csr[i] = make_float4(e.x, wS, wD, e.w);
}

// ---------------- weight prep (merged): Bp[kb][n][kk] bf16 + biases ----------------

__global__ __launch_bounds__(256) void prep_all(const ushort_t* W1s16, const float* W1s32,
                                                const ushort_t* W1d16, const float* W1d32,
                                                const ushort_t* b1s16, const float* b1s32,
                                                const ushort_t* b1d16, const float* b1d32,
                                                const ushort_t* W2s16, const float* W2s32,
                                                const ushort_t* W2d16, const float* W2d32,
                                                const ushort_t* b2s16, const float* b2s32,
                                                const ushort_t* b2d16, const float* b2d32,
                                                const ushort_t* Wro16, const float* Wro32,
                                                const ushort_t* bro16, const float* bro32) {
    int is16 = g_is16;
    int t = blockIdx.x * 256 + threadIdx.x;
    if (t < 2 * 32768) { // hidden layers
        int layer = t >> 15;
        int i = t & 32767;
        const ushort_t* Ws16 = layer ? W2s16 : W1s16;
        const float* Ws32 = layer ? W2s32 : W1s32;
        const ushort_t* Wd16 = layer ? W2d16 : W1d16;
        const float* Wd32 = layer ? W2d32 : W1d32;
        ushort_t* Bp = layer ? g_bp2 : g_bp1;
        int k = i >> 7, n = i & 127;
        ushort_t v;
        if (k < 128) {
            int idx = k * 128 + n;
            v = is16 ? Ws16[idx] : f2bf(Ws32[idx]);
        } else {
            int idx = (k - 128) * 128 + n;
            v = is16 ? Wd16[idx] : f2bf(Wd32[idx]);
        }
        int kb = k >> 5, kk = k & 31;
        Bp[((kb * 128 + n) << 5) + kk] = v;
        if (i < 128) {
            const ushort_t* bs16 = layer ? b2s16 : b1s16;
            const float* bs32 = layer ? b2s32 : b1s32;
            const ushort_t* bd16 = layer ? b2d16 : b1d16;
            const float* bd32 = layer ? b2d32 : b1d32;
            float a = is16 ? bf2f(bs16[i]) : bs32[i];
            float b = is16 ? bf2f(bd16[i]) : bd32[i];
            (layer ? g_bc2 : g_bc1)[i] = 0.5f * (a + b);
        }
    } else if (t < 2 * 32768 + 8192) { // readout
        int i = t - 2 * 32768;
        int k = i >> 6, n = i & 63;
        ushort_t v = is16 ? Wro16[i] : f2bf(Wro32[i]);
        int kb = k >> 5, kk = k & 31;
        g_bp3[((kb * 64 + n) << 5) + kk] = v;
        if (i < 64) g_bro[i] = is16 ? bf2f(bro16[i]) : bro32[i];
    }
}

// ---------------- gang-gather aggregation ----------------
// Empirical wall (r3/r5/r6/r8): aggregation time tracks VMEM *instruction*
// count only (invariant to bytes 2x, MLP 8x, L2-hit 63%, occupancy 4.7x).
// Fix: 4 entries per gather instruction. Each 16-lane group owns one node;
// lane r loads 16B (8 bf16 feats) of the group's entry row via dwordx4 ->
// one instruction services 4 rows. Accumulators in VGPRs (lane r: feats
// 8r..8r+7, fp32 x 2ch = 16 regs). Buckets node-major (n*NCH+c), chunk-
// sorted interior -> per-node range contiguous, soft-lockstep L2 window
// preserved. Group imbalance: loop to wave-max count, weights zeroed past
// own end. Batch-2 for latency overlap.

__global__ __launch_bounds__(256) void aggregate_gang(const ushort_t* __restrict__ xext, int ext) {
    int w = threadIdx.x >> 6;
    int lane = threadIdx.x & 63;
    int gsel = lane >> 4; // which of the wave's 4 nodes
    int r = lane & 15;    // feature sub-block: feats 8r..8r+7
    int node = (blockIdx.x * 4 + w) * 4 + gsel; // 3125 blocks * 16 nodes, exact
    const ushort_t* xin = ext ? (g_is16 ? xext : g_xcvt) : g_h1;

    int ks = g_offs2[node * NCH];
    int ke = g_offs2[node * NCH + NCH];
    int c = ke - ks;
    int cmax = c;
    cmax = max(cmax, __shfl_xor(cmax, 16));
    cmax = max(cmax, __shfl_xor(cmax, 32));

    float accS[8], accD[8];
#pragma unroll
    for (int f = 0; f < 8; f++) { accS[f] = 0.f; accD[f] = 0.f; }

    int k = 0;
    for (; k + 2 <= cmax; k += 2) {
        int i0 = ks + min(k, c - 1);
        int i1 = ks + min(k + 1, c - 1);
        float4 e0 = g_csr[i0];
        float4 e1 = g_csr[i1];
        bf16x8 v0 = *(const bf16x8*)(xin + (size_t)__float_as_int(e0.x) * 128 + r * 8);
        bf16x8 v1 = *(const bf16x8*)(xin + (size_t)__float_as_int(e1.x) * 128 + r * 8);
        float w0s = (k < c) ? e0.y : 0.f;
        float w0d = (k < c) ? e0.z : 0.f;
        float w1s = (k + 1 < c) ? e1.y : 0.f;
        float w1d = (k + 1 < c) ? e1.z : 0.f;
#pragma unroll
        for (int f = 0; f < 8; f++) {
            float x0 = bf2f((ushort_t)v0[f]);
            float x1 = bf2f((ushort_t)v1[f]);
            accS[f] = fmaf(w0s, x0, accS[f]);
            accD[f] = fmaf(w0d, x0, accD[f]);
            accS[f] = fmaf(w1s, x1, accS[f]);
            accD[f] = fmaf(w1d, x1, accD[f]);
        }
    }
    if (k < cmax) {
        int i0 = ks + min(k, c - 1);
        float4 e0 = g_csr[i0];
        bf16x8 v0 = *(const bf16x8*)(xin + (size_t)__float_as_int(e0.x) * 128 + r * 8);
        float w0s = (k < c) ? e0.y : 0.f;
        float w0d = (k < c) ? e0.z : 0.f;
#pragma unroll
        for (int f = 0; f < 8; f++) {
            float x0 = bf2f((ushort_t)v0[f]);
            accS[f] = fmaf(w0s, x0, accS[f]);
            accD[f] = fmaf(w0d, x0, accD[f]);
        }
    }

    // store: lane r covers feats 8r..8r+7 of its node's S and D halves (16B each)
    uint_t oS[4], oD[4];
#pragma unroll
    for (int p = 0; p < 4; p++) {
        oS[p] = ((uint_t)f2bf(accS[2 * p + 1]) << 16) | (uint_t)f2bf(accS[2 * p]);
        oD[p] = ((uint_t)f2bf(accD[2 * p + 1]) << 16) | (uint_t)f2bf(accD[2 * p]);
    }
    *(uint4*)(g_agg + (size_t)node * 256 + r * 8) = make_uint4(oS[0], oS[1], oS[2], oS[3]);
    *(uint4*)(g_agg + (size_t)node * 256 + 128 + r * 8) = make_uint4(oD[0], oD[1], oD[2], oD[3]);
}

// ---------------- MFMA GEMM: C = act(A[M][K]bf16 @ B + bias) ----------------
// LAYER 0: g_h1 = relu(g_agg @ g_bp1 + g_bc1), K=256, N=128
// LAYER 1: g_h2 = relu(g_agg @ g_bp2 + g_bc2), K=256, N=128
// LAYER 2: out  = g_h2 @ g_bp3 + g_bro, K=128, N=64 (dtype-flex store to outp)
// Verified layouts: A[m=lane&15][k=(lane>>4)*8+j]; B[k=(lane>>4)*8+j][n=lane&15];
//                   C col=lane&15, row=(lane>>4)*4+reg.

template <int LAYER, int KB, int NN, int NT, int RELU>
__global__ __launch_bounds__(256) void gemm_mfma(void* __restrict__ outp) {
    const ushort_t* A = (LAYER == 2) ? g_h2 : g_agg;
    const ushort_t* Bp = (LAYER == 0) ? g_bp1 : (LAYER == 1) ? g_bp2 : g_bp3;
    const float* bias = (LAYER == 0) ? g_bc1 : (LAYER == 1) ? g_bc2 : g_bro;
    const int M = N_NODES;
    const int K = KB * 32;
    int w = threadIdx.x >> 6; // wave 0..3
    int lane = threadIdx.x & 63;
    int c = lane & 15;
    int q = lane >> 4;
    int mBase = blockIdx.x * 64 + w * 16;

    f32x4 acc[NT];
#pragma unroll
    for (int nt = 0; nt < NT; nt++) acc[nt] = {0.f, 0.f, 0.f, 0.f};

    int arow = mBase + c;
    if (arow >= M) arow = M - 1; // clamp; stores guarded

#pragma unroll
    for (int kb = 0; kb < KB; kb++) {
        bf16x8 a = *(const bf16x8*)(A + (size_t)arow * K + kb * 32 + q * 8);
#pragma unroll
        for (int nt = 0; nt < NT; nt++) {
            bf16x8 b = *(const bf16x8*)(Bp + (((kb * NN + nt * 16 + c) << 5) + q * 8));
            acc[nt] = __builtin_amdgcn_mfma_f32_16x16x32_bf16(a, b, acc[nt], 0, 0, 0);
        }
    }

    int is16 = (LAYER == 2) ? g_is16 : 1;
#pragma unroll
    for (int nt = 0; nt < NT; nt++) {
        int n = nt * 16 + c;
        float bi = bias[n];
#pragma unroll
        for (int r = 0; r < 4; r++) {
            int m = mBase + q * 4 + r;
            if (m >= M) continue;
            float v = acc[nt][r] + bi;
            if (RELU) v = fmaxf(v, 0.f);
            if (LAYER == 0)
                g_h1[(size_t)m * NN + n] = f2bf(v);
            else if (LAYER == 1)
                g_h2[(size_t)m * NN + n] = f2bf(v);
            else if (is16)
                ((ushort_t*)outp)[(size_t)m * NN + n] = f2bf(v);
            else
                ((float*)outp)[(size_t)m * NN + n] = v;
        }
    }
}

// ---------------- launch ----------------

static inline int cdiv(int a, int b) { return (a + b - 1) / b; }

extern "C" void kernel_launch(void* const* d_in, const int* in_sizes, int n_in,
                              void* d_out, int out_size, void* d_ws, size_t ws_size,
                              hipStream_t stream) {
    const void* x = d_in[0]; // [50000][128]
    const int* eidx = (const int*)d_in[1];
    const void* theta = d_in[2];
    const void* W1s = d_in[3];
    const void* W1d = d_in[4];
    const void* b1s = d_in[5];
    const void* b1d = d_in[6];
    const void* W2s = d_in[7];
    const void* W2d = d_in[8];
    const void* b2s = d_in[9];
    const void* b2d = d_in[10];
    const void* Wro = d_in[11];
    const void* bro = d_in[12];
    (void)in_sizes; (void)n_in; (void)out_size; (void)d_ws; (void)ws_size;

    const int NB2 = cdiv(NE2, 1024); // 489

    detect_kernel<<<1, 64, 0, stream>>>((const uint_t*)x, eidx);
    conv_x<<<cdiv(N_NODES * 128 / 8, 256), 256, 0, stream>>>((const float*)x);
    init_cnt2<<<cdiv(N_NODES, 256), 256, 0, stream>>>();
    edge_cnt<<<cdiv(N_EDGES, 256), 256, 0, stream>>>(eidx);
    scan1<<<NB2, 1024, 0, stream>>>();
    scan2<<<1, 1, 0, stream>>>(NB2);
    scan3<<<cdiv(NE2, 256), 256, 0, stream>>>();
    fill_all<<<cdiv(N_EDGES, 256), 256, 0, stream>>>(eidx, (const ushort_t*)theta, (const float*)theta);
    deg_pass<<<cdiv(N_NODES, 256), 256, 0, stream>>>();
    finalize_w<<<cdiv(CSR_E, 256), 256, 0, stream>>>();
    prep_all<<<cdiv(2 * 32768 + 8192, 256), 256, 0, stream>>>(
        (const ushort_t*)W1s, (const float*)W1s, (const ushort_t*)W1d, (const float*)W1d,
        (const ushort_t*)b1s, (const float*)b1s, (const ushort_t*)b1d, (const float*)b1d,
        (const ushort_t*)W2s, (const float*)W2s, (const ushort_t*)W2d, (const float*)W2d,
        (const ushort_t*)b2s, (const float*)b2s, (const ushort_t*)b2d, (const float*)b2d,
        (const ushort_t*)Wro, (const float*)Wro, (const ushort_t*)bro, (const float*)bro);

    const int AB = N_NODES / 16; // 3125 blocks, 16 nodes each (exact)
    const int GB = cdiv(N_NODES, 64); // 782
    // layer 1
    aggregate_gang<<<AB, 256, 0, stream>>>((const ushort_t*)x, 1);
    gemm_mfma<0, 8, 128, 8, 1><<<GB, 256, 0, stream>>>(nullptr);
    // layer 2
    aggregate_gang<<<AB, 256, 0, stream>>>(nullptr, 0);
    gemm_mfma<1, 8, 128, 8, 1><<<GB, 256, 0, stream>>>(nullptr);
    // readout
    gemm_mfma<2, 4, 64, 4, 0><<<GB, 256, 0, stream>>>(d_out);
}

// Round 10
// 317.534 us; speedup vs baseline: 2.2517x; 1.2171x over previous
//
#include <hip/hip_runtime.h>
#include <hip/hip_fp16.h>

#define N_NODES 50000
#define N_EDGES 400000
#define CSR_E (2 * N_EDGES + N_NODES) /* 850000 */
#define NCH 10        /* source chunks */
#define CHW 5000      /* chunk width: 5000 nodes * 256B = 1.28MB window */
#define NE2 (N_NODES * NCH) /* buckets: (node, chunk), node-major contiguous */

typedef unsigned short ushort_t;
typedef unsigned int uint_t;
typedef __attribute__((ext_vector_type(8))) short bf16x8;
typedef __attribute__((ext_vector_type(4))) float f32x4;

__device__ __forceinline__ float bf2f(ushort_t u) {
    return __uint_as_float(((uint_t)u) << 16);
}
__device__ __forceinline__ ushort_t f2bf(float f) {
    uint_t b = __float_as_uint(f);
    b += 0x7FFFu + ((b >> 16) & 1u); // RNE
    return (ushort_t)(b >> 16);
}
// fp16 pair packing for CSR entry weights (low = S-channel, high = D-channel)
__device__ __forceinline__ uint_t packw(float a, float b) {
    return ((uint_t)__half_as_ushort(__float2half(b)) << 16) |
           (uint_t)__half_as_ushort(__float2half(a));
}
__device__ __forceinline__ float unpl(uint_t w) {
    return __half2float(__ushort_as_half((ushort_t)(w & 0xffffu)));
}
__device__ __forceinline__ float unph(uint_t w) {
    return __half2float(__ushort_as_half((ushort_t)(w >> 16)));
}

// ---------------- static device scratch (module BSS; d_ws untouched) ----------------
// NOTE: only reference these from device code (host sees shadow addresses - r4 fault).

__device__ int g_est;  // edge-index word stride: 1 = int32, 2 = int64
__device__ int g_is16; // 1 = float tensors bf16-packed, 0 = fp32
__device__ __align__(8) float2 g_dis2[N_NODES]; // (dis_s, dis_r)
__device__ int g_cnt2[NE2];
__device__ int g_offs2[NE2 + 1];
__device__ uint_t g_rank[N_EDGES]; // low16 = fwd rank, high16 = rev rank
__device__ int g_bsum[512];
__device__ int g_bbase[512];
__device__ __align__(16) uint2 g_csr8[CSR_E]; // {src, half2 w}: raw (out,in) -> final (wS',wD') src-folded
__device__ __align__(16) ushort_t g_agg[(size_t)N_NODES * 256]; // bf16 [N][s128|d128]
__device__ __align__(16) ushort_t g_h1[(size_t)N_NODES * 128];  // bf16
__device__ __align__(16) ushort_t g_h2[(size_t)N_NODES * 128];  // bf16
__device__ __align__(16) ushort_t g_xcvt[(size_t)N_NODES * 128]; // bf16 (fp32-input fallback)
__device__ __align__(16) ushort_t g_bp1[8 * 128 * 32]; // B packed [kb][n][kk] bf16
__device__ __align__(16) ushort_t g_bp2[8 * 128 * 32];
__device__ __align__(16) ushort_t g_bp3[4 * 64 * 32];
__device__ float g_bc1[128];
__device__ float g_bc2[128];
__device__ float g_bro[64];

// ---------------- detection + count init (merged) ----------------

__global__ __launch_bounds__(256) void init_detect(const uint_t* __restrict__ xw,
                                                   const int* __restrict__ eidx) {
    int n = blockIdx.x * 256 + threadIdx.x;
    if (n == 0) {
        int cnt = 0;
        for (int i = 0; i < 64; i++) {
            uint_t w = xw[i];
            int elo = (w >> 7) & 0xFF;
            if (elo >= 100 && elo <= 150) cnt++;
        }
        g_is16 = (cnt >= 48) ? 1 : 0;
        int any = 0;
        for (int i = 1; i < 128; i += 2) any |= eidx[i];
        g_est = any ? 1 : 2;
    }
    if (n < N_NODES) {
        int sc = n / CHW;
#pragma unroll
        for (int c = 0; c < NCH; c++) g_cnt2[n * NCH + c] = (c == sc) ? 1 : 0; // self-loop slot
    }
}

// fp32-input fallback: convert x to bf16 once (no-op when already bf16)
__global__ __launch_bounds__(256) void conv_x(const float* __restrict__ x32) {
    if (g_is16) return;
    int t = blockIdx.x * 256 + threadIdx.x;
    if (t >= N_NODES * 128 / 8) return;
    const float4* p = (const float4*)(x32 + t * 8);
    float4 a = p[0], b = p[1];
    ushort4 o0, o1;
    o0.x = f2bf(a.x); o0.y = f2bf(a.y); o0.z = f2bf(a.z); o0.w = f2bf(a.w);
    o1.x = f2bf(b.x); o1.y = f2bf(b.y); o1.z = f2bf(b.z); o1.w = f2bf(b.w);
    *(ushort4*)(g_xcvt + t * 8) = o0;
    *(ushort4*)(g_xcvt + t * 8 + 4) = o1;
}

// ---------------- edge counting; atomicAdd return value IS the bucket rank ----------------

__global__ __launch_bounds__(256) void edge_cnt(const int* __restrict__ eidx) {
    int e = blockIdx.x * 256 + threadIdx.x;
    if (e >= N_EDGES) return;
    int st = g_est;
    int s = eidx[(size_t)e * st];
    int r = eidx[((size_t)N_EDGES + e) * st];
    int rf = atomicAdd(&g_cnt2[r * NCH + s / CHW], 1); // fwd: dst=r, chunk of s
    int rr = atomicAdd(&g_cnt2[s * NCH + r / CHW], 1); // rev: dst=s, chunk of r
    g_rank[e] = (uint_t)rf | ((uint_t)rr << 16);       // ranks < 65536 (max degree ~100)
}

// ---------------- exclusive scan over NE2 counts ----------------

__global__ __launch_bounds__(1024) void scan1() {
    __shared__ int sd[1024];
    int i = blockIdx.x * 1024 + threadIdx.x;
    int v = (i < NE2) ? g_cnt2[i] : 0;
    sd[threadIdx.x] = v;
    __syncthreads();
    for (int o = 1; o < 1024; o <<= 1) {
        int tv = (threadIdx.x >= o) ? sd[threadIdx.x - o] : 0;
        __syncthreads();
        sd[threadIdx.x] += tv;
        __syncthreads();
    }
    if (i < NE2) g_offs2[i] = sd[threadIdx.x] - v;
    if (threadIdx.x == 1023) g_bsum[blockIdx.x] = sd[1023];
}

__global__ __launch_bounds__(512) void scan2(int nb) { // one block, parallel
    __shared__ int sd[512];
    int i = threadIdx.x;
    int v = (i < nb) ? g_bsum[i] : 0;
    sd[i] = v;
    __syncthreads();
    for (int o = 1; o < 512; o <<= 1) {
        int t = (i >= o) ? sd[i - o] : 0;
        __syncthreads();
        sd[i] += t;
        __syncthreads();
    }
    if (i < nb) g_bbase[i] = sd[i] - v;
    if (i == 0) g_offs2[NE2] = CSR_E; // sentinel
}

__global__ __launch_bounds__(256) void scan3() {
    int i = blockIdx.x * 256 + threadIdx.x;
    if (i < NE2) g_offs2[i] = g_offs2[i] + g_bbase[i >> 10];
}

// ---------------- CSR fill: ZERO atomics (rank + offs2), 8B entries ----------------

__global__ __launch_bounds__(256) void fill_all(const int* __restrict__ eidx,
                                                const ushort_t* __restrict__ th16,
                                                const float* __restrict__ th32) {
    int e = blockIdx.x * 256 + threadIdx.x;
    if (e < N_EDGES) {
        int st = g_est;
        int s = eidx[(size_t)e * st];
        int r = eidx[((size_t)N_EDGES + e) * st];
        float t = g_is16 ? bf2f(th16[e]) : th32[e];
        float sn, cs_;
        sincosf(t, &sn, &cs_);
        float c2 = cs_ * cs_;
        float s2 = sn * sn;
        uint_t rk = g_rank[e];
        int pf = g_offs2[r * NCH + s / CHW] + (int)(rk & 0xffffu);
        int pr = g_offs2[s * NCH + r / CHW] + (int)(rk >> 16);
        g_csr8[pf] = make_uint2((uint_t)s, packw(c2, s2)); // fwd: cs=s, out=c2, in=s2
        g_csr8[pr] = make_uint2((uint_t)r, packw(s2, c2)); // rev: cs=r, out=s2, in=c2
    }
    if (e < N_NODES) { // self-loop at rank 0 of its bucket
        int p = g_offs2[e * NCH + e / CHW];
        g_csr8[p] = make_uint2((uint_t)e, packw(1.0f, 1.0f));
    }
}

// ---------------- degrees (atomic-free; pairing identity) ----------------
// deg_s[n] = sum of in_w over node-n entries; deg_r[n] = sum of out_w.

__global__ __launch_bounds__(256) void deg_pass() {
    int n = blockIdx.x * 256 + threadIdx.x;
    if (n >= N_NODES) return;
    int kb = g_offs2[n * NCH];
    int ke = g_offs2[n * NCH + NCH];
    float ds = 0.f, dr = 0.f;
    for (int k = kb; k < ke; k++) {
        uint_t w = g_csr8[k].y;
        ds += unph(w); // in_w
        dr += unpl(w); // out_w
    }
    g_dis2[n] = make_float2(rsqrtf(ds + 1e-12f), rsqrtf(dr + 1e-12f));
}

// ---------------- finalize: fold SRC factors only (dst folded in agg epilogue) ----------------

__global__ __launch_bounds__(256) void finalize_w() {
    int i = blockIdx.x * 256 + threadIdx.x;
    if (i >= CSR_E) return;
    uint2 e = g_csr8[i];
    float2 d = g_dis2[e.x]; // (dis_s, dis_r) of src
    ((uint_t*)g_csr8)[2 * (size_t)i + 1] = packw(d.x * unpl(e.y), d.y * unph(e.y));
}

// ---------------- weight prep (merged): Bp[kb][n][kk] bf16 + biases ----------------

__global__ __launch_bounds__(256) void prep_all(const ushort_t* W1s16, const float* W1s32,
                                                const ushort_t* W1d16, const float* W1d32,
                                                const ushort_t* b1s16, const float* b1s32,
                                                const ushort_t* b1d16, const float* b1d32,
                                                const ushort_t* W2s16, const float* W2s32,
                                                const ushort_t* W2d16, const float* W2d32,
                                                const ushort_t* b2s16, const float* b2s32,
                                                const ushort_t* b2d16, const float* b2d32,
                                                const ushort_t* Wro16, const float* Wro32,
                                                const ushort_t* bro16, const float* bro32) {
    int is16 = g_is16;
    int t = blockIdx.x * 256 + threadIdx.x;
    if (t < 2 * 32768) { // hidden layers
        int layer = t >> 15;
        int i = t & 32767;
        const ushort_t* Ws16 = layer ? W2s16 : W1s16;
        const float* Ws32 = layer ? W2s32 : W1s32;
        const ushort_t* Wd16 = layer ? W2d16 : W1d16;
        const float* Wd32 = layer ? W2d32 : W1d32;
        ushort_t* Bp = layer ? g_bp2 : g_bp1;
        int k = i >> 7, n = i & 127;
        ushort_t v;
        if (k < 128) {
            int idx = k * 128 + n;
            v = is16 ? Ws16[idx] : f2bf(Ws32[idx]);
        } else {
            int idx = (k - 128) * 128 + n;
            v = is16 ? Wd16[idx] : f2bf(Wd32[idx]);
        }
        int kb = k >> 5, kk = k & 31;
        Bp[((kb * 128 + n) << 5) + kk] = v;
        if (i < 128) {
            const ushort_t* bs16 = layer ? b2s16 : b1s16;
            const float* bs32 = layer ? b2s32 : b1s32;
            const ushort_t* bd16 = layer ? b2d16 : b1d16;
            const float* bd32 = layer ? b2d32 : b1d32;
            float a = is16 ? bf2f(bs16[i]) : bs32[i];
            float b = is16 ? bf2f(bd16[i]) : bd32[i];
            (layer ? g_bc2 : g_bc1)[i] = 0.5f * (a + b);
        }
    } else if (t < 2 * 32768 + 8192) { // readout
        int i = t - 2 * 32768;
        int k = i >> 6, n = i & 63;
        ushort_t v = is16 ? Wro16[i] : f2bf(Wro32[i]);
        int kb = k >> 5, kk = k & 31;
        g_bp3[((kb * 64 + n) << 5) + kk] = v;
        if (i < 64) g_bro[i] = is16 ? bf2f(bro16[i]) : bro32[i];
    }
}

// ---------------- gang-gather aggregation (8B entries, dst-factor epilogue) ----------------
// 16-lane group owns one node; lane r loads 16B (8 bf16) of the entry row via
// dwordx4 -> 4 entries serviced per gather instruction (the r9 win). Entries are
// 8B {src, half2(wS',wD')} with src-dis pre-folded; epilogue applies
// 0.5*dis_r[n] (S) and 0.5*dis_s[n] (D). Buckets node-major, chunk-sorted
// interior -> contiguous per-node range, soft-lockstep L2 window.

__global__ __launch_bounds__(256) void aggregate_gang(const ushort_t* __restrict__ xext, int ext) {
    int w = threadIdx.x >> 6;
    int lane = threadIdx.x & 63;
    int gsel = lane >> 4; // which of the wave's 4 nodes
    int r = lane & 15;    // feature sub-block: feats 8r..8r+7
    int node = (blockIdx.x * 4 + w) * 4 + gsel; // 3125 blocks * 16 nodes, exact
    const ushort_t* xin = ext ? (g_is16 ? xext : g_xcvt) : g_h1;

    int ks = g_offs2[node * NCH];
    int ke = g_offs2[node * NCH + NCH];
    int c = ke - ks;
    int cmax = c;
    cmax = max(cmax, __shfl_xor(cmax, 16));
    cmax = max(cmax, __shfl_xor(cmax, 32));

    float accS[8], accD[8];
#pragma unroll
    for (int f = 0; f < 8; f++) { accS[f] = 0.f; accD[f] = 0.f; }

    int k = 0;
    for (; k + 2 <= cmax; k += 2) {
        int i0 = ks + min(k, c - 1);
        int i1 = ks + min(k + 1, c - 1);
        uint2 e0 = g_csr8[i0];
        uint2 e1 = g_csr8[i1];
        bf16x8 v0 = *(const bf16x8*)(xin + (size_t)e0.x * 128 + r * 8);
        bf16x8 v1 = *(const bf16x8*)(xin + (size_t)e1.x * 128 + r * 8);
        float w0s = (k < c) ? unpl(e0.y) : 0.f;
        float w0d = (k < c) ? unph(e0.y) : 0.f;
        float w1s = (k + 1 < c) ? unpl(e1.y) : 0.f;
        float w1d = (k + 1 < c) ? unph(e1.y) : 0.f;
#pragma unroll
        for (int f = 0; f < 8; f++) {
            float x0 = bf2f((ushort_t)v0[f]);
            float x1 = bf2f((ushort_t)v1[f]);
            accS[f] = fmaf(w0s, x0, accS[f]);
            accD[f] = fmaf(w0d, x0, accD[f]);
            accS[f] = fmaf(w1s, x1, accS[f]);
            accD[f] = fmaf(w1d, x1, accD[f]);
        }
    }
    if (k < cmax) {
        int i0 = ks + min(k, c - 1);
        uint2 e0 = g_csr8[i0];
        bf16x8 v0 = *(const bf16x8*)(xin + (size_t)e0.x * 128 + r * 8);
        float w0s = (k < c) ? unpl(e0.y) : 0.f;
        float w0d = (k < c) ? unph(e0.y) : 0.f;
#pragma unroll
        for (int f = 0; f < 8; f++) {
            float x0 = bf2f((ushort_t)v0[f]);
            accS[f] = fmaf(w0s, x0, accS[f]);
            accD[f] = fmaf(w0d, x0, accD[f]);
        }
    }

    float2 dn = g_dis2[node];
    float fs = 0.5f * dn.y; // S channel: 0.5 * dis_r[dst]
    float fd = 0.5f * dn.x; // D channel: 0.5 * dis_s[dst]
    uint_t oS[4], oD[4];
#pragma unroll
    for (int p = 0; p < 4; p++) {
        oS[p] = ((uint_t)f2bf(accS[2 * p + 1] * fs) << 16) | (uint_t)f2bf(accS[2 * p] * fs);
        oD[p] = ((uint_t)f2bf(accD[2 * p + 1] * fd) << 16) | (uint_t)f2bf(accD[2 * p] * fd);
    }
    *(uint4*)(g_agg + (size_t)node * 256 + r * 8) = make_uint4(oS[0], oS[1], oS[2], oS[3]);
    *(uint4*)(g_agg + (size_t)node * 256 + 128 + r * 8) = make_uint4(oD[0], oD[1], oD[2], oD[3]);
}

// ---------------- MFMA GEMM: C = act(A[M][K]bf16 @ B + bias) ----------------
// LAYER 0: g_h1 = relu(g_agg @ g_bp1 + g_bc1), K=256, N=128
// LAYER 1: g_h2 = relu(g_agg @ g_bp2 + g_bc2), K=256, N=128
// LAYER 2: out  = g_h2 @ g_bp3 + g_bro, K=128, N=64 (dtype-flex store to outp)
// Verified layouts: A[m=lane&15][k=(lane>>4)*8+j]; B[k=(lane>>4)*8+j][n=lane&15];
//                   C col=lane&15, row=(lane>>4)*4+reg.

template <int LAYER, int KB, int NN, int NT, int RELU>
__global__ __launch_bounds__(256) void gemm_mfma(void* __restrict__ outp) {
    const ushort_t* A = (LAYER == 2) ? g_h2 : g_agg;
    const ushort_t* Bp = (LAYER == 0) ? g_bp1 : (LAYER == 1) ? g_bp2 : g_bp3;
    const float* bias = (LAYER == 0) ? g_bc1 : (LAYER == 1) ? g_bc2 : g_bro;
    const int M = N_NODES;
    const int K = KB * 32;
    int w = threadIdx.x >> 6; // wave 0..3
    int lane = threadIdx.x & 63;
    int c = lane & 15;
    int q = lane >> 4;
    int mBase = blockIdx.x * 64 + w * 16;

    f32x4 acc[NT];
#pragma unroll
    for (int nt = 0; nt < NT; nt++) acc[nt] = {0.f, 0.f, 0.f, 0.f};

    int arow = mBase + c;
    if (arow >= M) arow = M - 1; // clamp; stores guarded

#pragma unroll
    for (int kb = 0; kb < KB; kb++) {
        bf16x8 a = *(const bf16x8*)(A + (size_t)arow * K + kb * 32 + q * 8);
#pragma unroll
        for (int nt = 0; nt < NT; nt++) {
            bf16x8 b = *(const bf16x8*)(Bp + (((kb * NN + nt * 16 + c) << 5) + q * 8));
            acc[nt] = __builtin_amdgcn_mfma_f32_16x16x32_bf16(a, b, acc[nt], 0, 0, 0);
        }
    }

    int is16 = (LAYER == 2) ? g_is16 : 1;
#pragma unroll
    for (int nt = 0; nt < NT; nt++) {
        int n = nt * 16 + c;
        float bi = bias[n];
#pragma unroll
        for (int r = 0; r < 4; r++) {
            int m = mBase + q * 4 + r;
            if (m >= M) continue;
            float v = acc[nt][r] + bi;
            if (RELU) v = fmaxf(v, 0.f);
            if (LAYER == 0)
                g_h1[(size_t)m * NN + n] = f2bf(v);
            else if (LAYER == 1)
                g_h2[(size_t)m * NN + n] = f2bf(v);
            else if (is16)
                ((ushort_t*)outp)[(size_t)m * NN + n] = f2bf(v);
            else
                ((float*)outp)[(size_t)m * NN + n] = v;
        }
    }
}

// ---------------- launch ----------------

static inline int cdiv(int a, int b) { return (a + b - 1) / b; }

extern "C" void kernel_launch(void* const* d_in, const int* in_sizes, int n_in,
                              void* d_out, int out_size, void* d_ws, size_t ws_size,
                              hipStream_t stream) {
    const void* x = d_in[0]; // [50000][128]
    const int* eidx = (const int*)d_in[1];
    const void* theta = d_in[2];
    const void* W1s = d_in[3];
    const void* W1d = d_in[4];
    const void* b1s = d_in[5];
    const void* b1d = d_in[6];
    const void* W2s = d_in[7];
    const void* W2d = d_in[8];
    const void* b2s = d_in[9];
    const void* b2d = d_in[10];
    const void* Wro = d_in[11];
    const void* bro = d_in[12];
    (void)in_sizes; (void)n_in; (void)out_size; (void)d_ws; (void)ws_size;

    const int NB2 = cdiv(NE2, 1024); // 489

    init_detect<<<cdiv(N_NODES, 256), 256, 0, stream>>>((const uint_t*)x, eidx);
    conv_x<<<cdiv(N_NODES * 128 / 8, 256), 256, 0, stream>>>((const float*)x);
    edge_cnt<<<cdiv(N_EDGES, 256), 256, 0, stream>>>(eidx);
    scan1<<<NB2, 1024, 0, stream>>>();
    scan2<<<1, 512, 0, stream>>>(NB2);
    scan3<<<cdiv(NE2, 256), 256, 0, stream>>>();
    fill_all<<<cdiv(N_EDGES, 256), 256, 0, stream>>>(eidx, (const ushort_t*)theta, (const float*)theta);
    deg_pass<<<cdiv(N_NODES, 256), 256, 0, stream>>>();
    finalize_w<<<cdiv(CSR_E, 256), 256, 0, stream>>>();
    prep_all<<<cdiv(2 * 32768 + 8192, 256), 256, 0, stream>>>(
        (const ushort_t*)W1s, (const float*)W1s, (const ushort_t*)W1d, (const float*)W1d,
        (const ushort_t*)b1s, (const float*)b1s, (const ushort_t*)b1d, (const float*)b1d,
        (const ushort_t*)W2s, (const float*)W2s, (const ushort_t*)W2d, (const float*)W2d,
        (const ushort_t*)b2s, (const float*)b2s, (const ushort_t*)b2d, (const float*)b2d,
        (const ushort_t*)Wro, (const float*)Wro, (const ushort_t*)bro, (const float*)bro);

    const int AB = N_NODES / 16; // 3125 blocks, 16 nodes each (exact)
    const int GB = cdiv(N_NODES, 64); // 782
    // layer 1
    aggregate_gang<<<AB, 256, 0, stream>>>((const ushort_t*)x, 1);
    gemm_mfma<0, 8, 128, 8, 1><<<GB, 256, 0, stream>>>(nullptr);
    // layer 2
    aggregate_gang<<<AB, 256, 0, stream>>>(nullptr, 0);
    gemm_mfma<1, 8, 128, 8, 1><<<GB, 256, 0, stream>>>(nullptr);
    // readout
    gemm_mfma<2, 4, 64, 4, 0><<<GB, 256, 0, stream>>>(d_out);
}